// Round 1
// baseline (1690.001 us; speedup 1.0000x reference)
//
#include <hip/hip_runtime.h>
#include <hip/hip_bf16.h>
#include <math.h>

#define BD 16
#define TT 96
#define NN 716
#define DD 64
#define MM 1196
#define ND 45824      // N*D
#define TP 97         // conv output length
#define COLS 2048     // 16 batches * 128 padded t
#define KPAD 736      // 716 padded to 23*32
#define KSTEPS 23

typedef __bf16 bf16x8 __attribute__((ext_vector_type(8)));
typedef float floatx4 __attribute__((ext_vector_type(4)));

__device__ __forceinline__ float gelu_f(float x){
    return 0.5f * x * (1.0f + erff(x * 0.70710678118654752f));
}
__device__ __forceinline__ unsigned short f2bf(float f){
    unsigned int u = __float_as_uint(f);
    u += 0x7fffu + ((u >> 16) & 1u);
    return (unsigned short)(u >> 16);
}

// ---------------- 1. depthwise conv + gelu -> H_T[col][c] bf16 ----------------
__global__ void k_conv(const float* __restrict__ x, const float* __restrict__ dww,
                       const float* __restrict__ dwb, unsigned short* __restrict__ HT){
    int gid = blockIdx.x * 256 + threadIdx.x;
    if (gid >= COLS * KPAD) return;
    int col = gid / KPAD;
    int c   = gid - col * KPAD;
    int b = col >> 7, t = col & 127;
    float r = 0.f;
    if (t < TP && c < NN){
        float s = dwb[c];
        #pragma unroll
        for (int j = 0; j < 12; ++j){
            int tp = t - 6 + j;
            if (tp >= 0 && tp < TT) s += x[((size_t)b*TT + tp)*NN + c] * dww[c*12 + j];
        }
        r = gelu_f(s);
    }
    HT[gid] = f2bf(r);
}

// ---------------- 2. big GEMM: q_pre[b][o] = mean_t gelu(pw_w@h + pw_b) -------
__launch_bounds__(256, 2)
__global__ void k_gemm(const float* __restrict__ A, const float* __restrict__ pwb,
                       const unsigned short* __restrict__ HT, float* __restrict__ Q){
    __shared__ unsigned short As[128*32];
    __shared__ unsigned short Bs[256*32];
    const int tid = threadIdx.x;
    const int m0 = blockIdx.x * 128;
    const int n0 = blockIdx.y * 256;
    const int wave = tid >> 6, lane = tid & 63;
    const int wm = wave >> 1, wn = wave & 1;
    const int quad = lane >> 4, l15 = lane & 15;
    floatx4 acc[4][8];
    #pragma unroll
    for (int i = 0; i < 4; ++i)
        #pragma unroll
        for (int j = 0; j < 8; ++j)
            acc[i][j] = (floatx4){0.f, 0.f, 0.f, 0.f};

    const int arow = tid >> 3;          // 0..31
    const int akq  = (tid & 7) * 4;     // 0..28
    const int brow = tid >> 2;          // 0..63
    const int bkq  = (tid & 3) * 8;     // 0..24

    for (int ks = 0; ks < KSTEPS; ++ks){
        const int k0 = ks * 32;
        #pragma unroll
        for (int p = 0; p < 4; ++p){
            int r = arow + p*32;
            float4 v = make_float4(0.f, 0.f, 0.f, 0.f);
            if (k0 + akq < NN)
                v = *reinterpret_cast<const float4*>(A + (size_t)(m0 + r)*NN + k0 + akq);
            ushort4 o;
            o.x = f2bf(v.x); o.y = f2bf(v.y); o.z = f2bf(v.z); o.w = f2bf(v.w);
            *reinterpret_cast<ushort4*>(&As[r*32 + akq]) = o;
        }
        #pragma unroll
        for (int p = 0; p < 4; ++p){
            int r = brow + p*64;
            uint4 v = *reinterpret_cast<const uint4*>(HT + (size_t)(n0 + r)*KPAD + k0 + bkq);
            *reinterpret_cast<uint4*>(&Bs[r*32 + bkq]) = v;
        }
        __syncthreads();
        bf16x8 af[4], bfr[8];
        #pragma unroll
        for (int i = 0; i < 4; ++i)
            af[i] = *reinterpret_cast<const bf16x8*>(&As[(wm*64 + i*16 + l15)*32 + quad*8]);
        #pragma unroll
        for (int j = 0; j < 8; ++j)
            bfr[j] = *reinterpret_cast<const bf16x8*>(&Bs[(wn*128 + j*16 + l15)*32 + quad*8]);
        #pragma unroll
        for (int i = 0; i < 4; ++i)
            #pragma unroll
            for (int j = 0; j < 8; ++j)
                acc[i][j] = __builtin_amdgcn_mfma_f32_16x16x32_bf16(af[i], bfr[j], acc[i][j], 0, 0, 0);
        __syncthreads();
    }
    // epilogue: gelu(+bias), mean over t (cols of this wave = batch bb, t = col_local)
    const int bb = blockIdx.y * 2 + wn;
    #pragma unroll
    for (int i = 0; i < 4; ++i){
        #pragma unroll
        for (int r = 0; r < 4; ++r){
            int og = m0 + wm*64 + i*16 + quad*4 + r;
            float pb = pwb[og];
            float s = 0.f;
            #pragma unroll
            for (int j = 0; j < 8; ++j){
                int t = j*16 + l15;
                if (t < TP) s += gelu_f(acc[i][j][r] + pb);
            }
            s += __shfl_xor(s, 1);
            s += __shfl_xor(s, 2);
            s += __shfl_xor(s, 4);
            s += __shfl_xor(s, 8);
            if (l15 == 0) Q[(size_t)bb*ND + og] = s * (1.0f/97.0f);
        }
    }
}

// ---------------- 3. LayerNorm over D=64, in place ----------------------------
__global__ void k_ln(float* __restrict__ QB, const float* __restrict__ g, const float* __restrict__ be){
    const int row = blockIdx.x*4 + (threadIdx.x >> 6);
    const int d = threadIdx.x & 63;
    float v = QB[(size_t)row*64 + d];
    float mu = v;
    #pragma unroll
    for (int off = 1; off <= 32; off <<= 1) mu += __shfl_xor(mu, off);
    mu *= (1.0f/64.0f);
    float dv = v - mu;
    float s2 = dv*dv;
    #pragma unroll
    for (int off = 1; off <= 32; off <<= 1) s2 += __shfl_xor(s2, off);
    float var = s2 * (1.0f/64.0f);
    QB[(size_t)row*64 + d] = dv / sqrtf(var + 1e-5f) * g[d] + be[d];
}

// ---------------- 4. per-batch q_flat inverse norm ----------------------------
__global__ void k_qnorm(const float* __restrict__ QB, float* __restrict__ QI){
    __shared__ float red[4];
    const int b = blockIdx.x, tid = threadIdx.x;
    float s = 0.f;
    for (int i = tid; i < ND; i += 256){ float v = QB[(size_t)b*ND + i]; s += v*v; }
    #pragma unroll
    for (int off = 32; off >= 1; off >>= 1) s += __shfl_xor(s, off);
    if ((tid & 63) == 0) red[tid >> 6] = s;
    __syncthreads();
    if (tid == 0){
        float t = red[0] + red[1] + red[2] + red[3];
        QI[b] = 1.0f / fmaxf(sqrtf(t), 1e-12f);
    }
}

// ---------------- 5. sim: fused mem-row norm + 16 dots + mask + diversity -----
__global__ void k_sim(const float* __restrict__ MB, const float* __restrict__ QB,
                      const float* __restrict__ QI,
                      const int* __restrict__ sq, const float* __restrict__ yq,
                      const int* __restrict__ ms, const float* __restrict__ my,
                      float* __restrict__ SIMB){
    const int grp = threadIdx.x >> 5, l = threadIdx.x & 31;
    const int m = blockIdx.x*8 + grp;
    if (m >= MM) return;
    const float4* mr = reinterpret_cast<const float4*>(MB + (size_t)m*ND);
    const float4* q4 = reinterpret_cast<const float4*>(QB);
    float dot[16];
    #pragma unroll
    for (int b = 0; b < 16; ++b) dot[b] = 0.f;
    float ss = 0.f;
    for (int i = l; i < ND/4; i += 32){
        float4 mv = mr[i];
        ss += mv.x*mv.x + mv.y*mv.y + mv.z*mv.z + mv.w*mv.w;
        #pragma unroll
        for (int b = 0; b < 16; ++b){
            float4 qv = q4[(size_t)b*(ND/4) + i];
            dot[b] += mv.x*qv.x + mv.y*qv.y + mv.z*qv.z + mv.w*qv.w;
        }
    }
    #pragma unroll
    for (int off = 16; off >= 1; off >>= 1){
        ss += __shfl_xor(ss, off);
        #pragma unroll
        for (int b = 0; b < 16; ++b) dot[b] += __shfl_xor(dot[b], off);
    }
    if (l == 0){
        float minv = 1.0f / fmaxf(sqrtf(ss), 1e-12f);
        int mse = ms[m]; float myv = my[m];
        #pragma unroll
        for (int b = 0; b < 16; ++b){
            float v = dot[b] * minv * QI[b];
            if (sq[b] != mse) v = -10000.0f;
            float dv = 1.0f - expf(-fabsf(yq[b] - myv) * 0.5f);
            v *= 0.5f + 0.5f*dv;
            SIMB[b*MM + m] = v;
        }
    }
}

// ---------------- 6. top-8 (ties -> lower index, matching lax.top_k) ----------
__global__ void k_topk(const float* __restrict__ SIMB, int* __restrict__ TK){
    __shared__ float sv[MM];
    __shared__ float rv[256];
    __shared__ int   ri[256];
    const int b = blockIdx.x, tid = threadIdx.x;
    for (int i = tid; i < MM; i += 256) sv[i] = SIMB[b*MM + i];
    __syncthreads();
    for (int it = 0; it < 8; ++it){
        float bv = -3.4e38f; int bi = 0x7fffffff;
        for (int i = tid; i < MM; i += 256){
            float v = sv[i];
            if (v > bv){ bv = v; bi = i; }
        }
        rv[tid] = bv; ri[tid] = bi;
        __syncthreads();
        for (int s = 128; s > 0; s >>= 1){
            if (tid < s){
                float ov = rv[tid+s]; int oi = ri[tid+s];
                if (ov > rv[tid] || (ov == rv[tid] && oi < ri[tid])){ rv[tid] = ov; ri[tid] = oi; }
            }
            __syncthreads();
        }
        if (tid == 0){ TK[b*8 + it] = ri[0]; sv[ri[0]] = -3.4e38f; }
        __syncthreads();
    }
}

// ---------------- 7. attention: qh/kh/vh + softmax over K=8 -> o --------------
__launch_bounds__(256)
__global__ void k_attn(const float* __restrict__ QB, const float* __restrict__ MB,
                       const int* __restrict__ TK,
                       const float* __restrict__ ipw, const float* __restrict__ ipb,
                       float* __restrict__ OW){
    __shared__ float wqT[64*65], wkT[64*65], wvT[64*65];
    __shared__ float ret[4][8][64];
    __shared__ float qr[4][64];
    __shared__ int tk[8];
    const int tid = threadIdx.x;
    const int b = blockIdx.y, n0 = blockIdx.x * 16;
    for (int idx = tid; idx < 4096; idx += 256){
        int e = idx >> 6, d = idx & 63;
        wqT[d*65 + e] = ipw[e*64 + d];
        wkT[d*65 + e] = ipw[(64 + e)*64 + d];
        wvT[d*65 + e] = ipw[(128 + e)*64 + d];
    }
    if (tid < 8) tk[tid] = TK[b*8 + tid];
    __syncthreads();
    const int wg = tid >> 6, e = tid & 63;
    const float bq = ipb[e], bk = ipb[64 + e], bv = ipb[128 + e];
    for (int ns = 0; ns < 4; ++ns){
        for (int idx = tid; idx < 2048; idx += 256){
            int gg = idx >> 9, kk = (idx >> 6) & 7, d = idx & 63;
            int n = n0 + ns*4 + gg;
            ret[gg][kk][d] = (n < NN) ? MB[(size_t)tk[kk]*ND + n*64 + d] : 0.f;
        }
        {
            int gg = tid >> 6, d = tid & 63;
            int n = n0 + ns*4 + gg;
            qr[gg][d] = (n < NN) ? QB[(size_t)b*ND + n*64 + d] : 0.f;
        }
        __syncthreads();
        const int n = n0 + ns*4 + wg;
        float qh = bq;
        float kh[8], vh[8];
        #pragma unroll
        for (int k = 0; k < 8; ++k){ kh[k] = bk; vh[k] = bv; }
        for (int d = 0; d < 64; ++d){
            float wq_ = wqT[d*65 + e], wk_ = wkT[d*65 + e], wv_ = wvT[d*65 + e];
            qh += qr[wg][d] * wq_;
            #pragma unroll
            for (int k = 0; k < 8; ++k){
                float rv2 = ret[wg][k][d];
                kh[k] += rv2 * wk_;
                vh[k] += rv2 * wv_;
            }
        }
        float sc[8];
        #pragma unroll
        for (int k = 0; k < 8; ++k){
            float p = qh * kh[k];
            p += __shfl_xor(p, 1); p += __shfl_xor(p, 2);
            p += __shfl_xor(p, 4); p += __shfl_xor(p, 8);
            sc[k] = p * 0.25f;   // 1/sqrt(hd)=1/4
        }
        float mx = sc[0];
        #pragma unroll
        for (int k = 1; k < 8; ++k) mx = fmaxf(mx, sc[k]);
        float sum = 0.f;
        #pragma unroll
        for (int k = 0; k < 8; ++k){ sc[k] = expf(sc[k] - mx); sum += sc[k]; }
        float inv = 1.0f / sum;
        float o = 0.f;
        #pragma unroll
        for (int k = 0; k < 8; ++k) o += sc[k] * inv * vh[k];
        if (n < NN) OW[(size_t)b*ND + n*64 + e] = o;
        __syncthreads();
    }
}

// ---------------- 8. h_cem = (o@aow^T+aob)@pjw^T+pjb --------------------------
__global__ void k_hcem(const float* __restrict__ OW, const float* __restrict__ aow,
                       const float* __restrict__ aob, const float* __restrict__ pjw,
                       const float* __restrict__ pjb, float* __restrict__ HC){
    __shared__ float aoT[64*65], pjT[64*65];
    __shared__ float ob[4][64], h1b[4][64];
    const int tid = threadIdx.x;
    for (int idx = tid; idx < 4096; idx += 256){
        int e = idx >> 6, d = idx & 63;
        aoT[d*65 + e] = aow[e*64 + d];
        pjT[d*65 + e] = pjw[e*64 + d];
    }
    const int g = tid >> 6, e = tid & 63;
    const size_t row = (size_t)blockIdx.x*4 + g;
    ob[g][e] = OW[row*64 + e];
    __syncthreads();
    float h1 = aob[e];
    for (int d = 0; d < 64; ++d) h1 += ob[g][d] * aoT[d*65 + e];
    h1b[g][e] = h1;
    __syncthreads();
    float h2 = pjb[e];
    for (int d = 0; d < 64; ++d) h2 += h1b[g][d] * pjT[d*65 + e];
    HC[row*64 + e] = h2;
}

// ---------------- 9. gates + mix + LN + heads (sigma, delta) ------------------
__launch_bounds__(256)
__global__ void k_final(const float* __restrict__ HC, const float* __restrict__ hlde,
                        const float* __restrict__ x, const float* __restrict__ gap,
                        const float* __restrict__ xpw, const float* __restrict__ xpb,
                        const float* __restrict__ g1w, const float* __restrict__ g1b,
                        const float* __restrict__ g2w, const float* __restrict__ g2b,
                        const float* __restrict__ opw, const float* __restrict__ opb,
                        const float* __restrict__ flg, const float* __restrict__ flb,
                        const float* __restrict__ u1w, const float* __restrict__ u1b,
                        const float* __restrict__ u2w, const float* __restrict__ u2b,
                        const float* __restrict__ dhw, const float* __restrict__ dhb,
                        float* __restrict__ sig, float* __restrict__ DLT){
    __shared__ float cat[16][256];
    __shared__ float gl[16][128];
    __shared__ float scl[16][3];
    __shared__ float gts[16][3];
    __shared__ float zl[16][64];
    __shared__ float z3[16][64];
    __shared__ float h4[16][32];
    const int tid = threadIdx.x;
    const int b = blockIdx.y, n0 = blockIdx.x * 16;
    for (int idx = tid; idx < 4096; idx += 256){
        int nl = idx >> 8, i = idx & 255;
        int n = n0 + nl;
        float v = 0.f;
        if (n < NN){
            if      (i < 64)  v = HC[((size_t)b*NN + n)*64 + i];
            else if (i < 128) v = hlde[((size_t)b*NN + n)*64 + (i - 64)];
            else if (i < 192) v = x[((size_t)b*TT + 95)*NN + n] * xpw[i - 128] + xpb[0];
            else              v = gap[i - 192];
        }
        cat[nl][i] = v;
    }
    __syncthreads();
    {   // g1: 128 outputs x 16 n
        int j = tid & 127, half = tid >> 7;
        float acc[8];
        #pragma unroll
        for (int q = 0; q < 8; ++q) acc[q] = 0.f;
        for (int i = 0; i < 256; ++i){
            float w = g1w[j*256 + i];
            #pragma unroll
            for (int q = 0; q < 8; ++q) acc[q] += cat[half*8 + q][i] * w;
        }
        float bj = g1b[j];
        #pragma unroll
        for (int q = 0; q < 8; ++q) gl[half*8 + q][j] = gelu_f(acc[q] + bj);
    }
    __syncthreads();
    if (tid < 48){
        int nl = tid / 3, c = tid % 3;
        float s = g2b[c];
        for (int i = 0; i < 128; ++i) s += gl[nl][i] * g2w[c*128 + i];
        scl[nl][c] = s;
    }
    __syncthreads();
    if (tid < 16){
        float a = scl[tid][0], b2 = scl[tid][1], c2 = scl[tid][2];
        float mx = fmaxf(a, fmaxf(b2, c2));
        float e0 = expf(a - mx), e1 = expf(b2 - mx), e2 = expf(c2 - mx);
        float inv = 1.0f / (e0 + e1 + e2);
        gts[tid][0] = e0*inv; gts[tid][1] = e1*inv; gts[tid][2] = e2*inv;
    }
    __syncthreads();
    const int wg = tid >> 6, e = tid & 63;
    #pragma unroll
    for (int it = 0; it < 4; ++it){
        int nl = it*4 + wg;
        zl[nl][e] = gts[nl][0]*cat[nl][e] + gts[nl][1]*cat[nl][64 + e] + gts[nl][2]*cat[nl][128 + e];
    }
    __syncthreads();
    for (int it = 0; it < 4; ++it){
        int nl = it*4 + wg;
        float zp = opb[e];
        for (int d = 0; d < 64; ++d) zp += zl[nl][d] * opw[e*64 + d];
        float mu = zp;
        #pragma unroll
        for (int off = 1; off <= 32; off <<= 1) mu += __shfl_xor(mu, off);
        mu *= (1.0f/64.0f);
        float dv = zp - mu;
        float s2 = dv*dv;
        #pragma unroll
        for (int off = 1; off <= 32; off <<= 1) s2 += __shfl_xor(s2, off);
        float var = s2 * (1.0f/64.0f);
        float zn = dv / sqrtf(var + 1e-5f) * flg[e] + flb[e];
        z3[nl][e] = zn;
        float p = zn * dhw[e];
        #pragma unroll
        for (int off = 1; off <= 32; off <<= 1) p += __shfl_xor(p, off);
        if (e == 0){
            int n = n0 + nl;
            if (n < NN) DLT[b*NN + n] = p + dhb[0];
        }
    }
    __syncthreads();
    {
        int u = tid & 31, grp = tid >> 5;
        #pragma unroll
        for (int it = 0; it < 2; ++it){
            int nl = it*8 + grp;
            float s = u1b[u];
            for (int d = 0; d < 64; ++d) s += z3[nl][d] * u1w[u*64 + d];
            h4[nl][u] = gelu_f(s);
        }
    }
    __syncthreads();
    if (tid < 192){
        int o = tid % 12, nl = tid / 12;
        int n = n0 + nl;
        float s = u2b[o];
        for (int i = 0; i < 32; ++i) s += h4[nl][i] * u2w[o*32 + i];
        float sp = (s > 20.f) ? s : log1pf(expf(s));
        if (n < NN) sig[((size_t)b*NN + n)*12 + o] = sp + 1e-6f;
    }
}

// ---------------- 10. z_out = x + delta broadcast over t ----------------------
__global__ void k_zout(const float* __restrict__ x, const float* __restrict__ DLT,
                       float* __restrict__ out){
    int idx = blockIdx.x * 256 + threadIdx.x;
    if (idx >= BD*TT*NN) return;
    int b = idx / (TT*NN);
    int n = idx % NN;
    out[idx] = x[idx] + DLT[b*NN + n];
}

extern "C" void kernel_launch(void* const* d_in, const int* in_sizes, int n_in,
                              void* d_out, int out_size, void* d_ws, size_t ws_size,
                              hipStream_t stream){
    const float* x    = (const float*)d_in[0];
    const int*   sq   = (const int*)  d_in[1];
    const float* yq   = (const float*)d_in[2];
    const float* hlde = (const float*)d_in[3];
    const float* dww  = (const float*)d_in[4];
    const float* dwb  = (const float*)d_in[5];
    const float* pww  = (const float*)d_in[6];
    const float* pwb  = (const float*)d_in[7];
    const float* encg = (const float*)d_in[8];
    const float* encb = (const float*)d_in[9];
    const float* mb   = (const float*)d_in[10];
    const int*   ms   = (const int*)  d_in[11];
    const float* my   = (const float*)d_in[12];
    const float* ipw  = (const float*)d_in[13];
    const float* ipb  = (const float*)d_in[14];
    const float* aow  = (const float*)d_in[15];
    const float* aob  = (const float*)d_in[16];
    const float* pjw  = (const float*)d_in[17];
    const float* pjb  = (const float*)d_in[18];
    const float* gap  = (const float*)d_in[19];
    const float* xpw  = (const float*)d_in[20];
    const float* xpb  = (const float*)d_in[21];
    const float* g1w  = (const float*)d_in[22];
    const float* g1b  = (const float*)d_in[23];
    const float* g2w  = (const float*)d_in[24];
    const float* g2b  = (const float*)d_in[25];
    const float* opw  = (const float*)d_in[26];
    const float* opb  = (const float*)d_in[27];
    const float* dhw  = (const float*)d_in[28];
    const float* dhb  = (const float*)d_in[29];
    const float* flg  = (const float*)d_in[30];
    const float* flb  = (const float*)d_in[31];
    const float* u1w  = (const float*)d_in[32];
    const float* u1b  = (const float*)d_in[33];
    const float* u2w  = (const float*)d_in[34];
    const float* u2b  = (const float*)d_in[35];

    char* ws = (char*)d_ws;
    unsigned short* HT = (unsigned short*)(ws + 0);         // 3,014,656 B
    float* QB   = (float*)(ws + 3014656);                   // 2,932,736 B
    float* QI   = (float*)(ws + 5947392);                   // 256 B
    float* SIMB = (float*)(ws + 5947648);                   // 76,544 B
    int*   TK   = (int*)  (ws + 6024192);                   // 512 B
    float* OWB  = (float*)(ws + 6024704);                   // 2,932,736 B
    float* HCB  = (float*)(ws + 8957440);                   // 2,932,736 B
    float* DLT  = (float*)(ws + 11890176);                  // 45,824 B

    float* out = (float*)d_out;
    float* sig = out + 1099776;

    k_conv <<<dim3(5888),   dim3(256), 0, stream>>>(x, dww, dwb, HT);
    k_gemm <<<dim3(358, 8), dim3(256), 0, stream>>>(pww, pwb, HT, QB);
    k_ln   <<<dim3(2864),   dim3(256), 0, stream>>>(QB, encg, encb);
    k_qnorm<<<dim3(16),     dim3(256), 0, stream>>>(QB, QI);
    k_sim  <<<dim3(150),    dim3(256), 0, stream>>>(mb, QB, QI, sq, yq, ms, my, SIMB);
    k_topk <<<dim3(16),     dim3(256), 0, stream>>>(SIMB, TK);
    k_attn <<<dim3(45, 16), dim3(256), 0, stream>>>(QB, mb, TK, ipw, ipb, OWB);
    k_hcem <<<dim3(2864),   dim3(256), 0, stream>>>(OWB, aow, aob, pjw, pjb, HCB);
    k_final<<<dim3(45, 16), dim3(256), 0, stream>>>(HCB, hlde, x, gap, xpw, xpb,
            g1w, g1b, g2w, g2b, opw, opb, flg, flb, u1w, u1b, u2w, u2b, dhw, dhb,
            sig, DLT);
    k_zout <<<dim3(4296),   dim3(256), 0, stream>>>(x, DLT, out);
}

// Round 2
// 1072.954 us; speedup vs baseline: 1.5751x; 1.5751x over previous
//
#include <hip/hip_runtime.h>
#include <hip/hip_bf16.h>
#include <math.h>

#define BD 16
#define TT 96
#define NN 716
#define DD 64
#define MM 1196
#define ND 45824      // N*D
#define ND4 11456     // ND/4
#define TP 97         // conv output length
#define COLS 2048     // 16 batches * 128 padded t
#define KPAD 736      // 716 padded to 23*32
#define KSTEPS 23
#define NCH 16        // ND chunks for k_sim
#define CH4 716       // float4 per chunk (11456/16)

typedef __bf16 bf16x8 __attribute__((ext_vector_type(8)));
typedef float floatx4 __attribute__((ext_vector_type(4)));

__device__ __forceinline__ float gelu_f(float x){
    return 0.5f * x * (1.0f + erff(x * 0.70710678118654752f));
}
__device__ __forceinline__ unsigned short f2bf(float f){
    unsigned int u = __float_as_uint(f);
    u += 0x7fffu + ((u >> 16) & 1u);
    return (unsigned short)(u >> 16);
}

// ---------------- 1. depthwise conv + gelu -> H_T[col][c] bf16 ----------------
__global__ void k_conv(const float* __restrict__ x, const float* __restrict__ dww,
                       const float* __restrict__ dwb, unsigned short* __restrict__ HT){
    int gid = blockIdx.x * 256 + threadIdx.x;
    if (gid >= COLS * KPAD) return;
    int col = gid / KPAD;
    int c   = gid - col * KPAD;
    int b = col >> 7, t = col & 127;
    float r = 0.f;
    if (t < TP && c < NN){
        float s = dwb[c];
        #pragma unroll
        for (int j = 0; j < 12; ++j){
            int tp = t - 6 + j;
            if (tp >= 0 && tp < TT) s += x[((size_t)b*TT + tp)*NN + c] * dww[c*12 + j];
        }
        r = gelu_f(s);
    }
    HT[gid] = f2bf(r);
}

// ---------------- 2. big GEMM: q_pre[b][o] = mean_t gelu(pw_w@h + pw_b) -------
__launch_bounds__(256, 2)
__global__ void k_gemm(const float* __restrict__ A, const float* __restrict__ pwb,
                       const unsigned short* __restrict__ HT, float* __restrict__ Q){
    __shared__ unsigned short As[128*32];
    __shared__ unsigned short Bs[256*32];
    const int tid = threadIdx.x;
    const int m0 = blockIdx.x * 128;
    const int n0 = blockIdx.y * 256;
    const int wave = tid >> 6, lane = tid & 63;
    const int wm = wave >> 1, wn = wave & 1;
    const int quad = lane >> 4, l15 = lane & 15;
    floatx4 acc[4][8];
    #pragma unroll
    for (int i = 0; i < 4; ++i)
        #pragma unroll
        for (int j = 0; j < 8; ++j)
            acc[i][j] = (floatx4){0.f, 0.f, 0.f, 0.f};

    const int arow = tid >> 3;          // 0..31
    const int akq  = (tid & 7) * 4;     // 0..28
    const int brow = tid >> 2;          // 0..63
    const int bkq  = (tid & 3) * 8;     // 0..24

    for (int ks = 0; ks < KSTEPS; ++ks){
        const int k0 = ks * 32;
        #pragma unroll
        for (int p = 0; p < 4; ++p){
            int r = arow + p*32;
            float4 v = make_float4(0.f, 0.f, 0.f, 0.f);
            if (k0 + akq < NN)
                v = *reinterpret_cast<const float4*>(A + (size_t)(m0 + r)*NN + k0 + akq);
            ushort4 o;
            o.x = f2bf(v.x); o.y = f2bf(v.y); o.z = f2bf(v.z); o.w = f2bf(v.w);
            *reinterpret_cast<ushort4*>(&As[r*32 + akq]) = o;
        }
        #pragma unroll
        for (int p = 0; p < 4; ++p){
            int r = brow + p*64;
            uint4 v = *reinterpret_cast<const uint4*>(HT + (size_t)(n0 + r)*KPAD + k0 + bkq);
            *reinterpret_cast<uint4*>(&Bs[r*32 + bkq]) = v;
        }
        __syncthreads();
        bf16x8 af[4], bfr[8];
        #pragma unroll
        for (int i = 0; i < 4; ++i)
            af[i] = *reinterpret_cast<const bf16x8*>(&As[(wm*64 + i*16 + l15)*32 + quad*8]);
        #pragma unroll
        for (int j = 0; j < 8; ++j)
            bfr[j] = *reinterpret_cast<const bf16x8*>(&Bs[(wn*128 + j*16 + l15)*32 + quad*8]);
        #pragma unroll
        for (int i = 0; i < 4; ++i)
            #pragma unroll
            for (int j = 0; j < 8; ++j)
                acc[i][j] = __builtin_amdgcn_mfma_f32_16x16x32_bf16(af[i], bfr[j], acc[i][j], 0, 0, 0);
        __syncthreads();
    }
    // epilogue: gelu(+bias), mean over t (cols of this wave = batch bb, t = col_local)
    const int bb = blockIdx.y * 2 + wn;
    #pragma unroll
    for (int i = 0; i < 4; ++i){
        #pragma unroll
        for (int r = 0; r < 4; ++r){
            int og = m0 + wm*64 + i*16 + quad*4 + r;
            float pb = pwb[og];
            float s = 0.f;
            #pragma unroll
            for (int j = 0; j < 8; ++j){
                int t = j*16 + l15;
                if (t < TP) s += gelu_f(acc[i][j][r] + pb);
            }
            s += __shfl_xor(s, 1);
            s += __shfl_xor(s, 2);
            s += __shfl_xor(s, 4);
            s += __shfl_xor(s, 8);
            if (l15 == 0) Q[(size_t)bb*ND + og] = s * (1.0f/97.0f);
        }
    }
}

// ---------------- 3. LayerNorm over D=64, in place ----------------------------
__global__ void k_ln(float* __restrict__ QB, const float* __restrict__ g, const float* __restrict__ be){
    const int row = blockIdx.x*4 + (threadIdx.x >> 6);
    const int d = threadIdx.x & 63;
    float v = QB[(size_t)row*64 + d];
    float mu = v;
    #pragma unroll
    for (int off = 1; off <= 32; off <<= 1) mu += __shfl_xor(mu, off);
    mu *= (1.0f/64.0f);
    float dv = v - mu;
    float s2 = dv*dv;
    #pragma unroll
    for (int off = 1; off <= 32; off <<= 1) s2 += __shfl_xor(s2, off);
    float var = s2 * (1.0f/64.0f);
    QB[(size_t)row*64 + d] = dv / sqrtf(var + 1e-5f) * g[d] + be[d];
}

// ---------------- 4. per-batch q_flat inverse norm ----------------------------
__global__ void k_qnorm(const float* __restrict__ QB, float* __restrict__ QI){
    __shared__ float red[4];
    const int b = blockIdx.x, tid = threadIdx.x;
    float s = 0.f;
    for (int i = tid; i < ND; i += 256){ float v = QB[(size_t)b*ND + i]; s += v*v; }
    #pragma unroll
    for (int off = 32; off >= 1; off >>= 1) s += __shfl_xor(s, off);
    if ((tid & 63) == 0) red[tid >> 6] = s;
    __syncthreads();
    if (tid == 0){
        float t = red[0] + red[1] + red[2] + red[3];
        QI[b] = 1.0f / fmaxf(sqrtf(t), 1e-12f);
    }
}

// ---------------- 5. sim partial dots: wave = 4 mem rows x 1 ND chunk ---------
// P[ch][m][16] = partial dot(mem_m, q_b) over chunk ch; PSS[ch][m] = partial |mem_m|^2
__launch_bounds__(256)
__global__ void k_sim(const float* __restrict__ MB, const float* __restrict__ QB,
                      float* __restrict__ P, float* __restrict__ PSS){
    const int wave = threadIdx.x >> 6, lane = threadIdx.x & 63;
    const int m0 = blockIdx.x * 16 + wave * 4;
    if (m0 >= MM) return;
    const int ch = blockIdx.y;
    const int c0 = ch * CH4;
    const float4* q4  = reinterpret_cast<const float4*>(QB) + c0;
    const float4* mr  = reinterpret_cast<const float4*>(MB) + (size_t)m0*ND4 + c0;
    float dot[4][16];
    float ss[4];
    #pragma unroll
    for (int r = 0; r < 4; ++r){
        ss[r] = 0.f;
        #pragma unroll
        for (int b = 0; b < 16; ++b) dot[r][b] = 0.f;
    }
    for (int i = lane; i < CH4; i += 64){
        float4 mv[4];
        mv[0] = mr[i];
        mv[1] = mr[ND4 + i];
        mv[2] = mr[2*ND4 + i];
        mv[3] = mr[3*ND4 + i];
        #pragma unroll
        for (int r = 0; r < 4; ++r)
            ss[r] += mv[r].x*mv[r].x + mv[r].y*mv[r].y + mv[r].z*mv[r].z + mv[r].w*mv[r].w;
        #pragma unroll
        for (int b = 0; b < 16; ++b){
            float4 qv = q4[(size_t)b*ND4 + i];
            #pragma unroll
            for (int r = 0; r < 4; ++r)
                dot[r][b] += mv[r].x*qv.x + mv[r].y*qv.y + mv[r].z*qv.z + mv[r].w*qv.w;
        }
    }
    #pragma unroll
    for (int off = 1; off <= 32; off <<= 1){
        #pragma unroll
        for (int r = 0; r < 4; ++r){
            ss[r] += __shfl_xor(ss[r], off);
            #pragma unroll
            for (int b = 0; b < 16; ++b) dot[r][b] += __shfl_xor(dot[r][b], off);
        }
    }
    if (lane == 0){
        #pragma unroll
        for (int r = 0; r < 4; ++r){
            PSS[(size_t)ch*MM + m0 + r] = ss[r];
            #pragma unroll
            for (int b = 0; b < 16; ++b)
                P[((size_t)ch*MM + m0 + r)*16 + b] = dot[r][b];
        }
    }
}

// ---------------- 6. chunk-reduce + mask/diversity + top-8 --------------------
__global__ void k_topk(const float* __restrict__ P, const float* __restrict__ PSS,
                       const float* __restrict__ QI,
                       const int* __restrict__ sq, const float* __restrict__ yq,
                       const int* __restrict__ ms, const float* __restrict__ my,
                       int* __restrict__ TK){
    __shared__ float sv[MM];
    __shared__ float rv[256];
    __shared__ int   ri[256];
    const int b = blockIdx.x, tid = threadIdx.x;
    const float qi = QI[b];
    const int   sqb = sq[b];
    const float yqb = yq[b];
    for (int m = tid; m < MM; m += 256){
        float rd = 0.f, st = 0.f;
        #pragma unroll
        for (int c = 0; c < NCH; ++c){
            rd += P[((size_t)c*MM + m)*16 + b];
            st += PSS[(size_t)c*MM + m];
        }
        float v = rd * (1.0f / fmaxf(sqrtf(st), 1e-12f)) * qi;
        if (sqb != ms[m]) v = -10000.0f;
        float dv = 1.0f - expf(-fabsf(yqb - my[m]) * 0.5f);
        sv[m] = v * (0.5f + 0.5f*dv);
    }
    __syncthreads();
    for (int it = 0; it < 8; ++it){
        float bv = -3.4e38f; int bi = 0x7fffffff;
        for (int i = tid; i < MM; i += 256){
            float v = sv[i];
            if (v > bv){ bv = v; bi = i; }
        }
        rv[tid] = bv; ri[tid] = bi;
        __syncthreads();
        for (int s = 128; s > 0; s >>= 1){
            if (tid < s){
                float ov = rv[tid+s]; int oi = ri[tid+s];
                if (ov > rv[tid] || (ov == rv[tid] && oi < ri[tid])){ rv[tid] = ov; ri[tid] = oi; }
            }
            __syncthreads();
        }
        if (tid == 0){ TK[b*8 + it] = ri[0]; sv[ri[0]] = -3.4e38f; }
        __syncthreads();
    }
}

// ---------------- 7. attention: qh/kh/vh + softmax over K=8 -> o --------------
__launch_bounds__(256)
__global__ void k_attn(const float* __restrict__ QB, const float* __restrict__ MB,
                       const int* __restrict__ TK,
                       const float* __restrict__ ipw, const float* __restrict__ ipb,
                       float* __restrict__ OW){
    __shared__ float wqT[64*65], wkT[64*65], wvT[64*65];
    __shared__ float ret[4][8][64];
    __shared__ float qr[4][64];
    __shared__ int tk[8];
    const int tid = threadIdx.x;
    const int b = blockIdx.y, n0 = blockIdx.x * 16;
    for (int idx = tid; idx < 4096; idx += 256){
        int e = idx >> 6, d = idx & 63;
        wqT[d*65 + e] = ipw[e*64 + d];
        wkT[d*65 + e] = ipw[(64 + e)*64 + d];
        wvT[d*65 + e] = ipw[(128 + e)*64 + d];
    }
    if (tid < 8) tk[tid] = TK[b*8 + tid];
    __syncthreads();
    const int wg = tid >> 6, e = tid & 63;
    const float bq = ipb[e], bk = ipb[64 + e], bv = ipb[128 + e];
    for (int ns = 0; ns < 4; ++ns){
        for (int idx = tid; idx < 2048; idx += 256){
            int gg = idx >> 9, kk = (idx >> 6) & 7, d = idx & 63;
            int n = n0 + ns*4 + gg;
            ret[gg][kk][d] = (n < NN) ? MB[(size_t)tk[kk]*ND + n*64 + d] : 0.f;
        }
        {
            int gg = tid >> 6, d = tid & 63;
            int n = n0 + ns*4 + gg;
            qr[gg][d] = (n < NN) ? QB[(size_t)b*ND + n*64 + d] : 0.f;
        }
        __syncthreads();
        const int n = n0 + ns*4 + wg;
        float qh = bq;
        float kh[8], vh[8];
        #pragma unroll
        for (int k = 0; k < 8; ++k){ kh[k] = bk; vh[k] = bv; }
        for (int d = 0; d < 64; ++d){
            float wq_ = wqT[d*65 + e], wk_ = wkT[d*65 + e], wv_ = wvT[d*65 + e];
            qh += qr[wg][d] * wq_;
            #pragma unroll
            for (int k = 0; k < 8; ++k){
                float rv2 = ret[wg][k][d];
                kh[k] += rv2 * wk_;
                vh[k] += rv2 * wv_;
            }
        }
        float sc[8];
        #pragma unroll
        for (int k = 0; k < 8; ++k){
            float p = qh * kh[k];
            p += __shfl_xor(p, 1); p += __shfl_xor(p, 2);
            p += __shfl_xor(p, 4); p += __shfl_xor(p, 8);
            sc[k] = p * 0.25f;   // 1/sqrt(hd)=1/4
        }
        float mx = sc[0];
        #pragma unroll
        for (int k = 1; k < 8; ++k) mx = fmaxf(mx, sc[k]);
        float sum = 0.f;
        #pragma unroll
        for (int k = 0; k < 8; ++k){ sc[k] = expf(sc[k] - mx); sum += sc[k]; }
        float inv = 1.0f / sum;
        float o = 0.f;
        #pragma unroll
        for (int k = 0; k < 8; ++k) o += sc[k] * inv * vh[k];
        if (n < NN) OW[(size_t)b*ND + n*64 + e] = o;
        __syncthreads();
    }
}

// ---------------- 8. h_cem = (o@aow^T+aob)@pjw^T+pjb --------------------------
__global__ void k_hcem(const float* __restrict__ OW, const float* __restrict__ aow,
                       const float* __restrict__ aob, const float* __restrict__ pjw,
                       const float* __restrict__ pjb, float* __restrict__ HC){
    __shared__ float aoT[64*65], pjT[64*65];
    __shared__ float ob[4][64], h1b[4][64];
    const int tid = threadIdx.x;
    for (int idx = tid; idx < 4096; idx += 256){
        int e = idx >> 6, d = idx & 63;
        aoT[d*65 + e] = aow[e*64 + d];
        pjT[d*65 + e] = pjw[e*64 + d];
    }
    const int g = tid >> 6, e = tid & 63;
    const size_t row = (size_t)blockIdx.x*4 + g;
    ob[g][e] = OW[row*64 + e];
    __syncthreads();
    float h1 = aob[e];
    for (int d = 0; d < 64; ++d) h1 += ob[g][d] * aoT[d*65 + e];
    h1b[g][e] = h1;
    __syncthreads();
    float h2 = pjb[e];
    for (int d = 0; d < 64; ++d) h2 += h1b[g][d] * pjT[d*65 + e];
    HC[row*64 + e] = h2;
}

// ---------------- 9. gates + mix + LN + heads (sigma, delta) ------------------
__launch_bounds__(256)
__global__ void k_final(const float* __restrict__ HC, const float* __restrict__ hlde,
                        const float* __restrict__ x, const float* __restrict__ gap,
                        const float* __restrict__ xpw, const float* __restrict__ xpb,
                        const float* __restrict__ g1w, const float* __restrict__ g1b,
                        const float* __restrict__ g2w, const float* __restrict__ g2b,
                        const float* __restrict__ opw, const float* __restrict__ opb,
                        const float* __restrict__ flg, const float* __restrict__ flb,
                        const float* __restrict__ u1w, const float* __restrict__ u1b,
                        const float* __restrict__ u2w, const float* __restrict__ u2b,
                        const float* __restrict__ dhw, const float* __restrict__ dhb,
                        float* __restrict__ sig, float* __restrict__ DLT){
    __shared__ float cat[16][256];
    __shared__ float gl[16][128];
    __shared__ float scl[16][3];
    __shared__ float gts[16][3];
    __shared__ float zl[16][64];
    __shared__ float z3[16][64];
    __shared__ float h4[16][32];
    const int tid = threadIdx.x;
    const int b = blockIdx.y, n0 = blockIdx.x * 16;
    for (int idx = tid; idx < 4096; idx += 256){
        int nl = idx >> 8, i = idx & 255;
        int n = n0 + nl;
        float v = 0.f;
        if (n < NN){
            if      (i < 64)  v = HC[((size_t)b*NN + n)*64 + i];
            else if (i < 128) v = hlde[((size_t)b*NN + n)*64 + (i - 64)];
            else if (i < 192) v = x[((size_t)b*TT + 95)*NN + n] * xpw[i - 128] + xpb[0];
            else              v = gap[i - 192];
        }
        cat[nl][i] = v;
    }
    __syncthreads();
    {   // g1: 128 outputs x 16 n
        int j = tid & 127, half = tid >> 7;
        float acc[8];
        #pragma unroll
        for (int q = 0; q < 8; ++q) acc[q] = 0.f;
        for (int i = 0; i < 256; ++i){
            float w = g1w[j*256 + i];
            #pragma unroll
            for (int q = 0; q < 8; ++q) acc[q] += cat[half*8 + q][i] * w;
        }
        float bj = g1b[j];
        #pragma unroll
        for (int q = 0; q < 8; ++q) gl[half*8 + q][j] = gelu_f(acc[q] + bj);
    }
    __syncthreads();
    if (tid < 48){
        int nl = tid / 3, c = tid % 3;
        float s = g2b[c];
        for (int i = 0; i < 128; ++i) s += gl[nl][i] * g2w[c*128 + i];
        scl[nl][c] = s;
    }
    __syncthreads();
    if (tid < 16){
        float a = scl[tid][0], b2 = scl[tid][1], c2 = scl[tid][2];
        float mx = fmaxf(a, fmaxf(b2, c2));
        float e0 = expf(a - mx), e1 = expf(b2 - mx), e2 = expf(c2 - mx);
        float inv = 1.0f / (e0 + e1 + e2);
        gts[tid][0] = e0*inv; gts[tid][1] = e1*inv; gts[tid][2] = e2*inv;
    }
    __syncthreads();
    const int wg = tid >> 6, e = tid & 63;
    #pragma unroll
    for (int it = 0; it < 4; ++it){
        int nl = it*4 + wg;
        zl[nl][e] = gts[nl][0]*cat[nl][e] + gts[nl][1]*cat[nl][64 + e] + gts[nl][2]*cat[nl][128 + e];
    }
    __syncthreads();
    for (int it = 0; it < 4; ++it){
        int nl = it*4 + wg;
        float zp = opb[e];
        for (int d = 0; d < 64; ++d) zp += zl[nl][d] * opw[e*64 + d];
        float mu = zp;
        #pragma unroll
        for (int off = 1; off <= 32; off <<= 1) mu += __shfl_xor(mu, off);
        mu *= (1.0f/64.0f);
        float dv = zp - mu;
        float s2 = dv*dv;
        #pragma unroll
        for (int off = 1; off <= 32; off <<= 1) s2 += __shfl_xor(s2, off);
        float var = s2 * (1.0f/64.0f);
        float zn = dv / sqrtf(var + 1e-5f) * flg[e] + flb[e];
        z3[nl][e] = zn;
        float p = zn * dhw[e];
        #pragma unroll
        for (int off = 1; off <= 32; off <<= 1) p += __shfl_xor(p, off);
        if (e == 0){
            int n = n0 + nl;
            if (n < NN) DLT[b*NN + n] = p + dhb[0];
        }
    }
    __syncthreads();
    {
        int u = tid & 31, grp = tid >> 5;
        #pragma unroll
        for (int it = 0; it < 2; ++it){
            int nl = it*8 + grp;
            float s = u1b[u];
            for (int d = 0; d < 64; ++d) s += z3[nl][d] * u1w[u*64 + d];
            h4[nl][u] = gelu_f(s);
        }
    }
    __syncthreads();
    if (tid < 192){
        int o = tid % 12, nl = tid / 12;
        int n = n0 + nl;
        float s = u2b[o];
        for (int i = 0; i < 32; ++i) s += h4[nl][i] * u2w[o*32 + i];
        float sp = (s > 20.f) ? s : log1pf(expf(s));
        if (n < NN) sig[((size_t)b*NN + n)*12 + o] = sp + 1e-6f;
    }
}

// ---------------- 10. z_out = x + delta broadcast over t ----------------------
__global__ void k_zout(const float* __restrict__ x, const float* __restrict__ DLT,
                       float* __restrict__ out){
    int idx = blockIdx.x * 256 + threadIdx.x;
    if (idx >= BD*TT*NN) return;
    int b = idx / (TT*NN);
    int n = idx % NN;
    out[idx] = x[idx] + DLT[b*NN + n];
}

extern "C" void kernel_launch(void* const* d_in, const int* in_sizes, int n_in,
                              void* d_out, int out_size, void* d_ws, size_t ws_size,
                              hipStream_t stream){
    const float* x    = (const float*)d_in[0];
    const int*   sq   = (const int*)  d_in[1];
    const float* yq   = (const float*)d_in[2];
    const float* hlde = (const float*)d_in[3];
    const float* dww  = (const float*)d_in[4];
    const float* dwb  = (const float*)d_in[5];
    const float* pww  = (const float*)d_in[6];
    const float* pwb  = (const float*)d_in[7];
    const float* encg = (const float*)d_in[8];
    const float* encb = (const float*)d_in[9];
    const float* mb   = (const float*)d_in[10];
    const int*   ms   = (const int*)  d_in[11];
    const float* my   = (const float*)d_in[12];
    const float* ipw  = (const float*)d_in[13];
    const float* ipb  = (const float*)d_in[14];
    const float* aow  = (const float*)d_in[15];
    const float* aob  = (const float*)d_in[16];
    const float* pjw  = (const float*)d_in[17];
    const float* pjb  = (const float*)d_in[18];
    const float* gap  = (const float*)d_in[19];
    const float* xpw  = (const float*)d_in[20];
    const float* xpb  = (const float*)d_in[21];
    const float* g1w  = (const float*)d_in[22];
    const float* g1b  = (const float*)d_in[23];
    const float* g2w  = (const float*)d_in[24];
    const float* g2b  = (const float*)d_in[25];
    const float* opw  = (const float*)d_in[26];
    const float* opb  = (const float*)d_in[27];
    const float* dhw  = (const float*)d_in[28];
    const float* dhb  = (const float*)d_in[29];
    const float* flg  = (const float*)d_in[30];
    const float* flb  = (const float*)d_in[31];
    const float* u1w  = (const float*)d_in[32];
    const float* u1b  = (const float*)d_in[33];
    const float* u2w  = (const float*)d_in[34];
    const float* u2b  = (const float*)d_in[35];

    char* ws = (char*)d_ws;
    unsigned short* HT = (unsigned short*)(ws + 0);         // 3,014,656 B (dead after k_gemm)
    // P/PSS reuse the HT region (k_sim runs after k_gemm): 1,224,704 + 76,544 B
    float* P    = (float*)(ws + 0);
    float* PSS  = (float*)(ws + 1224704);
    float* QB   = (float*)(ws + 3014656);                   // 2,932,736 B
    float* QI   = (float*)(ws + 5947392);                   // 256 B
    int*   TK   = (int*)  (ws + 6024192);                   // 512 B
    float* OWB  = (float*)(ws + 6024704);                   // 2,932,736 B
    float* HCB  = (float*)(ws + 8957440);                   // 2,932,736 B
    float* DLT  = (float*)(ws + 11890176);                  // 45,824 B

    float* out = (float*)d_out;
    float* sig = out + 1099776;

    k_conv <<<dim3(5888),   dim3(256), 0, stream>>>(x, dww, dwb, HT);
    k_gemm <<<dim3(358, 8), dim3(256), 0, stream>>>(pww, pwb, HT, QB);
    k_ln   <<<dim3(2864),   dim3(256), 0, stream>>>(QB, encg, encb);
    k_qnorm<<<dim3(16),     dim3(256), 0, stream>>>(QB, QI);
    k_sim  <<<dim3(75, 16), dim3(256), 0, stream>>>(mb, QB, P, PSS);
    k_topk <<<dim3(16),     dim3(256), 0, stream>>>(P, PSS, QI, sq, yq, ms, my, TK);
    k_attn <<<dim3(45, 16), dim3(256), 0, stream>>>(QB, mb, TK, ipw, ipb, OWB);
    k_hcem <<<dim3(2864),   dim3(256), 0, stream>>>(OWB, aow, aob, pjw, pjb, HCB);
    k_final<<<dim3(45, 16), dim3(256), 0, stream>>>(HCB, hlde, x, gap, xpw, xpb,
            g1w, g1b, g2w, g2b, opw, opb, flg, flb, u1w, u1b, u2w, u2b, dhw, dhb,
            sig, DLT);
    k_zout <<<dim3(4296),   dim3(256), 0, stream>>>(x, DLT, out);
}

// Round 3
// 959.532 us; speedup vs baseline: 1.7613x; 1.1182x over previous
//
#include <hip/hip_runtime.h>
#include <hip/hip_bf16.h>
#include <math.h>

#define BD 16
#define TT 96
#define NN 716
#define DD 64
#define MM 1196
#define ND 45824      // N*D
#define ND4 11456     // ND/4
#define TP 97         // conv output length
#define COLS 2048     // 16 batches * 128 padded t
#define KPAD 736      // 716 padded to 23*32
#define KSTEPS 23
#define NCH 16        // ND chunks for k_sim
#define CH4 716       // float4 per chunk (11456/16)

typedef __bf16 bf16x8 __attribute__((ext_vector_type(8)));
typedef float floatx4 __attribute__((ext_vector_type(4)));

#define GLDS16(g, l) __builtin_amdgcn_global_load_lds( \
    (const __attribute__((address_space(1))) void*)(g), \
    (__attribute__((address_space(3))) void*)(l), 16, 0, 0)

__device__ __forceinline__ float gelu_f(float x){
    return 0.5f * x * (1.0f + erff(x * 0.70710678118654752f));
}
__device__ __forceinline__ unsigned short f2bf(float f){
    unsigned int u = __float_as_uint(f);
    u += 0x7fffu + ((u >> 16) & 1u);
    return (unsigned short)(u >> 16);
}

// ---------------- 0. cast pw_w fp32 -> bf16, K-pad 716->736 -------------------
__global__ void k_cast(const float* __restrict__ A, unsigned short* __restrict__ Abf){
    int gid = blockIdx.x * 256 + threadIdx.x;
    if (gid >= ND * 92) return;               // 92 = 736/8 threads per row
    int row = gid / 92;
    int kq  = (gid - row * 92) * 8;
    const float* src = A + (size_t)row * NN + kq;
    ushort4 o0, o1;
    if (kq + 8 <= NN){
        float4 a = *reinterpret_cast<const float4*>(src);
        float4 b = *reinterpret_cast<const float4*>(src + 4);
        o0.x = f2bf(a.x); o0.y = f2bf(a.y); o0.z = f2bf(a.z); o0.w = f2bf(a.w);
        o1.x = f2bf(b.x); o1.y = f2bf(b.y); o1.z = f2bf(b.z); o1.w = f2bf(b.w);
    } else {
        unsigned short t[8];
        #pragma unroll
        for (int j = 0; j < 8; ++j) t[j] = (kq + j < NN) ? f2bf(src[j]) : (unsigned short)0;
        o0 = make_ushort4(t[0], t[1], t[2], t[3]);
        o1 = make_ushort4(t[4], t[5], t[6], t[7]);
    }
    unsigned short* dst = Abf + (size_t)row * KPAD + kq;
    *reinterpret_cast<ushort4*>(dst)     = o0;
    *reinterpret_cast<ushort4*>(dst + 4) = o1;
}

// ---------------- 1. depthwise conv + gelu -> H_T[col][c] bf16 ----------------
__global__ void k_conv(const float* __restrict__ x, const float* __restrict__ dww,
                       const float* __restrict__ dwb, unsigned short* __restrict__ HT){
    int gid = blockIdx.x * 256 + threadIdx.x;
    if (gid >= COLS * KPAD) return;
    int col = gid / KPAD;
    int c   = gid - col * KPAD;
    int b = col >> 7, t = col & 127;
    float r = 0.f;
    if (t < TP && c < NN){
        float s = dwb[c];
        #pragma unroll
        for (int j = 0; j < 12; ++j){
            int tp = t - 6 + j;
            if (tp >= 0 && tp < TT) s += x[((size_t)b*TT + tp)*NN + c] * dww[c*12 + j];
        }
        r = gelu_f(s);
    }
    HT[gid] = f2bf(r);
}

// ---------------- 2. big GEMM via global_load_lds -----------------------------
// C[m0+128][n0+256], A bf16 (Abf, K-stride 736), B bf16 (HT, K-stride 736)
__launch_bounds__(256, 2)
__global__ void k_gemm(const unsigned short* __restrict__ Abf, const float* __restrict__ pwb,
                       const unsigned short* __restrict__ HT, float* __restrict__ Q){
    __shared__ unsigned short As[128*32];
    __shared__ unsigned short Bs[256*32];
    const int tid = threadIdx.x;
    const int n0 = blockIdx.x * 256;    // N-tile inner for A-tile L2 reuse
    const int m0 = blockIdx.y * 128;
    const int wave = tid >> 6, lane = tid & 63;
    const int wm = wave >> 1, wn = wave & 1;
    const int quad = lane >> 4, l15 = lane & 15;
    const int lrow = lane >> 2, lk = (lane & 3) * 8;
    floatx4 acc[4][8];
    #pragma unroll
    for (int i = 0; i < 4; ++i)
        #pragma unroll
        for (int j = 0; j < 8; ++j)
            acc[i][j] = (floatx4){0.f, 0.f, 0.f, 0.f};

    // wave staging bases: A calls 2w,2w+1 cover As rows 32w..32w+31;
    // B calls 4w..4w+3 cover Bs rows 64w..64w+63. LDS dest is wave-uniform + lane*16.
    const unsigned short* ag = Abf + (size_t)(m0 + 32*wave + lrow)*KPAD + lk;
    const unsigned short* bg = HT  + (size_t)(n0 + 64*wave + lrow)*KPAD + lk;
    unsigned short* asl = As + wave*1024;   // shorts (c=2w -> byte 2048w)
    unsigned short* bsl = Bs + wave*2048;   // shorts (c=4w -> byte 4096w)

    for (int ks = 0; ks < KSTEPS; ++ks){
        const int k0 = ks * 32;
        GLDS16(ag + k0,            asl);
        GLDS16(ag + 16*KPAD + k0,  asl + 512);
        GLDS16(bg + k0,            bsl);
        GLDS16(bg + 16*KPAD + k0,  bsl + 512);
        GLDS16(bg + 32*KPAD + k0,  bsl + 1024);
        GLDS16(bg + 48*KPAD + k0,  bsl + 1536);
        __syncthreads();
        bf16x8 af[4], bfr[8];
        #pragma unroll
        for (int i = 0; i < 4; ++i)
            af[i] = *reinterpret_cast<const bf16x8*>(&As[(wm*64 + i*16 + l15)*32 + quad*8]);
        #pragma unroll
        for (int j = 0; j < 8; ++j)
            bfr[j] = *reinterpret_cast<const bf16x8*>(&Bs[(wn*128 + j*16 + l15)*32 + quad*8]);
        #pragma unroll
        for (int i = 0; i < 4; ++i)
            #pragma unroll
            for (int j = 0; j < 8; ++j)
                acc[i][j] = __builtin_amdgcn_mfma_f32_16x16x32_bf16(af[i], bfr[j], acc[i][j], 0, 0, 0);
        __syncthreads();
    }
    // epilogue: gelu(+bias), mean over t
    const int bb = blockIdx.x * 2 + wn;
    #pragma unroll
    for (int i = 0; i < 4; ++i){
        #pragma unroll
        for (int r = 0; r < 4; ++r){
            int og = m0 + wm*64 + i*16 + quad*4 + r;
            float pb = pwb[og];
            float s = 0.f;
            #pragma unroll
            for (int j = 0; j < 8; ++j){
                int t = j*16 + l15;
                if (t < TP) s += gelu_f(acc[i][j][r] + pb);
            }
            s += __shfl_xor(s, 1);
            s += __shfl_xor(s, 2);
            s += __shfl_xor(s, 4);
            s += __shfl_xor(s, 8);
            if (l15 == 0) Q[(size_t)bb*ND + og] = s * (1.0f/97.0f);
        }
    }
}

// ---------------- 3. LayerNorm over D=64, in place ----------------------------
__global__ void k_ln(float* __restrict__ QB, const float* __restrict__ g, const float* __restrict__ be){
    const int row = blockIdx.x*4 + (threadIdx.x >> 6);
    const int d = threadIdx.x & 63;
    float v = QB[(size_t)row*64 + d];
    float mu = v;
    #pragma unroll
    for (int off = 1; off <= 32; off <<= 1) mu += __shfl_xor(mu, off);
    mu *= (1.0f/64.0f);
    float dv = v - mu;
    float s2 = dv*dv;
    #pragma unroll
    for (int off = 1; off <= 32; off <<= 1) s2 += __shfl_xor(s2, off);
    float var = s2 * (1.0f/64.0f);
    QB[(size_t)row*64 + d] = dv / sqrtf(var + 1e-5f) * g[d] + be[d];
}

// ---------------- 4. per-batch q_flat inverse norm ----------------------------
__global__ void k_qnorm(const float* __restrict__ QB, float* __restrict__ QI){
    __shared__ float red[4];
    const int b = blockIdx.x, tid = threadIdx.x;
    float s = 0.f;
    for (int i = tid; i < ND; i += 256){ float v = QB[(size_t)b*ND + i]; s += v*v; }
    #pragma unroll
    for (int off = 32; off >= 1; off >>= 1) s += __shfl_xor(s, off);
    if ((tid & 63) == 0) red[tid >> 6] = s;
    __syncthreads();
    if (tid == 0){
        float t = red[0] + red[1] + red[2] + red[3];
        QI[b] = 1.0f / fmaxf(sqrtf(t), 1e-12f);
    }
}

// ---------------- 5. sim partial dots: wave = 4 mem rows x 1 ND chunk ---------
__launch_bounds__(256)
__global__ void k_sim(const float* __restrict__ MB, const float* __restrict__ QB,
                      float* __restrict__ P, float* __restrict__ PSS){
    const int wave = threadIdx.x >> 6, lane = threadIdx.x & 63;
    const int m0 = blockIdx.x * 16 + wave * 4;
    if (m0 >= MM) return;
    const int ch = blockIdx.y;
    const int c0 = ch * CH4;
    const float4* q4  = reinterpret_cast<const float4*>(QB) + c0;
    const float4* mr  = reinterpret_cast<const float4*>(MB) + (size_t)m0*ND4 + c0;
    float dot[4][16];
    float ss[4];
    #pragma unroll
    for (int r = 0; r < 4; ++r){
        ss[r] = 0.f;
        #pragma unroll
        for (int b = 0; b < 16; ++b) dot[r][b] = 0.f;
    }
    for (int i = lane; i < CH4; i += 64){
        float4 mv[4];
        mv[0] = mr[i];
        mv[1] = mr[ND4 + i];
        mv[2] = mr[2*ND4 + i];
        mv[3] = mr[3*ND4 + i];
        #pragma unroll
        for (int r = 0; r < 4; ++r)
            ss[r] += mv[r].x*mv[r].x + mv[r].y*mv[r].y + mv[r].z*mv[r].z + mv[r].w*mv[r].w;
        #pragma unroll
        for (int b = 0; b < 16; ++b){
            float4 qv = q4[(size_t)b*ND4 + i];
            #pragma unroll
            for (int r = 0; r < 4; ++r)
                dot[r][b] += mv[r].x*qv.x + mv[r].y*qv.y + mv[r].z*qv.z + mv[r].w*qv.w;
        }
    }
    #pragma unroll
    for (int off = 1; off <= 32; off <<= 1){
        #pragma unroll
        for (int r = 0; r < 4; ++r){
            ss[r] += __shfl_xor(ss[r], off);
            #pragma unroll
            for (int b = 0; b < 16; ++b) dot[r][b] += __shfl_xor(dot[r][b], off);
        }
    }
    if (lane == 0){
        #pragma unroll
        for (int r = 0; r < 4; ++r){
            PSS[(size_t)ch*MM + m0 + r] = ss[r];
            #pragma unroll
            for (int b = 0; b < 16; ++b)
                P[((size_t)ch*MM + m0 + r)*16 + b] = dot[r][b];
        }
    }
}

// ---------------- 6. chunk-reduce + mask/diversity + top-8 --------------------
__global__ void k_topk(const float* __restrict__ P, const float* __restrict__ PSS,
                       const float* __restrict__ QI,
                       const int* __restrict__ sq, const float* __restrict__ yq,
                       const int* __restrict__ ms, const float* __restrict__ my,
                       int* __restrict__ TK){
    __shared__ float sv[MM];
    __shared__ float rv[256];
    __shared__ int   ri[256];
    const int b = blockIdx.x, tid = threadIdx.x;
    const float qi = QI[b];
    const int   sqb = sq[b];
    const float yqb = yq[b];
    for (int m = tid; m < MM; m += 256){
        float rd = 0.f, st = 0.f;
        #pragma unroll
        for (int c = 0; c < NCH; ++c){
            rd += P[((size_t)c*MM + m)*16 + b];
            st += PSS[(size_t)c*MM + m];
        }
        float v = rd * (1.0f / fmaxf(sqrtf(st), 1e-12f)) * qi;
        if (sqb != ms[m]) v = -10000.0f;
        float dv = 1.0f - expf(-fabsf(yqb - my[m]) * 0.5f);
        sv[m] = v * (0.5f + 0.5f*dv);
    }
    __syncthreads();
    for (int it = 0; it < 8; ++it){
        float bv = -3.4e38f; int bi = 0x7fffffff;
        for (int i = tid; i < MM; i += 256){
            float v = sv[i];
            if (v > bv){ bv = v; bi = i; }
        }
        rv[tid] = bv; ri[tid] = bi;
        __syncthreads();
        for (int s = 128; s > 0; s >>= 1){
            if (tid < s){
                float ov = rv[tid+s]; int oi = ri[tid+s];
                if (ov > rv[tid] || (ov == rv[tid] && oi < ri[tid])){ rv[tid] = ov; ri[tid] = oi; }
            }
            __syncthreads();
        }
        if (tid == 0){ TK[b*8 + it] = ri[0]; sv[ri[0]] = -3.4e38f; }
        __syncthreads();
    }
}

// ---------------- 7. attention: qh/kh/vh + softmax over K=8 -> o --------------
__launch_bounds__(256)
__global__ void k_attn(const float* __restrict__ QB, const float* __restrict__ MB,
                       const int* __restrict__ TK,
                       const float* __restrict__ ipw, const float* __restrict__ ipb,
                       float* __restrict__ OW){
    __shared__ float wqT[64*65], wkT[64*65], wvT[64*65];
    __shared__ float ret[4][8][64];
    __shared__ float qr[4][64];
    __shared__ int tk[8];
    const int tid = threadIdx.x;
    const int b = blockIdx.y, n0 = blockIdx.x * 16;
    for (int idx = tid; idx < 4096; idx += 256){
        int e = idx >> 6, d = idx & 63;
        wqT[d*65 + e] = ipw[e*64 + d];
        wkT[d*65 + e] = ipw[(64 + e)*64 + d];
        wvT[d*65 + e] = ipw[(128 + e)*64 + d];
    }
    if (tid < 8) tk[tid] = TK[b*8 + tid];
    __syncthreads();
    const int wg = tid >> 6, e = tid & 63;
    const float bq = ipb[e], bk = ipb[64 + e], bv = ipb[128 + e];
    for (int ns = 0; ns < 4; ++ns){
        for (int idx = tid; idx < 2048; idx += 256){
            int gg = idx >> 9, kk = (idx >> 6) & 7, d = idx & 63;
            int n = n0 + ns*4 + gg;
            ret[gg][kk][d] = (n < NN) ? MB[(size_t)tk[kk]*ND + n*64 + d] : 0.f;
        }
        {
            int gg = tid >> 6, d = tid & 63;
            int n = n0 + ns*4 + gg;
            qr[gg][d] = (n < NN) ? QB[(size_t)b*ND + n*64 + d] : 0.f;
        }
        __syncthreads();
        const int n = n0 + ns*4 + wg;
        float qh = bq;
        float kh[8], vh[8];
        #pragma unroll
        for (int k = 0; k < 8; ++k){ kh[k] = bk; vh[k] = bv; }
        for (int d = 0; d < 64; ++d){
            float wq_ = wqT[d*65 + e], wk_ = wkT[d*65 + e], wv_ = wvT[d*65 + e];
            qh += qr[wg][d] * wq_;
            #pragma unroll
            for (int k = 0; k < 8; ++k){
                float rv2 = ret[wg][k][d];
                kh[k] += rv2 * wk_;
                vh[k] += rv2 * wv_;
            }
        }
        float sc[8];
        #pragma unroll
        for (int k = 0; k < 8; ++k){
            float p = qh * kh[k];
            p += __shfl_xor(p, 1); p += __shfl_xor(p, 2);
            p += __shfl_xor(p, 4); p += __shfl_xor(p, 8);
            sc[k] = p * 0.25f;
        }
        float mx = sc[0];
        #pragma unroll
        for (int k = 1; k < 8; ++k) mx = fmaxf(mx, sc[k]);
        float sum = 0.f;
        #pragma unroll
        for (int k = 0; k < 8; ++k){ sc[k] = expf(sc[k] - mx); sum += sc[k]; }
        float inv = 1.0f / sum;
        float o = 0.f;
        #pragma unroll
        for (int k = 0; k < 8; ++k) o += sc[k] * inv * vh[k];
        if (n < NN) OW[(size_t)b*ND + n*64 + e] = o;
        __syncthreads();
    }
}

// ---------------- 8. h_cem = (o@aow^T+aob)@pjw^T+pjb --------------------------
__global__ void k_hcem(const float* __restrict__ OW, const float* __restrict__ aow,
                       const float* __restrict__ aob, const float* __restrict__ pjw,
                       const float* __restrict__ pjb, float* __restrict__ HC){
    __shared__ float aoT[64*65], pjT[64*65];
    __shared__ float ob[4][64], h1b[4][64];
    const int tid = threadIdx.x;
    for (int idx = tid; idx < 4096; idx += 256){
        int e = idx >> 6, d = idx & 63;
        aoT[d*65 + e] = aow[e*64 + d];
        pjT[d*65 + e] = pjw[e*64 + d];
    }
    const int g = tid >> 6, e = tid & 63;
    const size_t row = (size_t)blockIdx.x*4 + g;
    ob[g][e] = OW[row*64 + e];
    __syncthreads();
    float h1 = aob[e];
    for (int d = 0; d < 64; ++d) h1 += ob[g][d] * aoT[d*65 + e];
    h1b[g][e] = h1;
    __syncthreads();
    float h2 = pjb[e];
    for (int d = 0; d < 64; ++d) h2 += h1b[g][d] * pjT[d*65 + e];
    HC[row*64 + e] = h2;
}

// ---------------- 9. gates + mix + LN + heads (sigma, delta) ------------------
__launch_bounds__(256)
__global__ void k_final(const float* __restrict__ HC, const float* __restrict__ hlde,
                        const float* __restrict__ x, const float* __restrict__ gap,
                        const float* __restrict__ xpw, const float* __restrict__ xpb,
                        const float* __restrict__ g1w, const float* __restrict__ g1b,
                        const float* __restrict__ g2w, const float* __restrict__ g2b,
                        const float* __restrict__ opw, const float* __restrict__ opb,
                        const float* __restrict__ flg, const float* __restrict__ flb,
                        const float* __restrict__ u1w, const float* __restrict__ u1b,
                        const float* __restrict__ u2w, const float* __restrict__ u2b,
                        const float* __restrict__ dhw, const float* __restrict__ dhb,
                        float* __restrict__ sig, float* __restrict__ DLT){
    __shared__ float cat[16][256];
    __shared__ float gl[16][128];
    __shared__ float scl[16][3];
    __shared__ float gts[16][3];
    __shared__ float zl[16][64];
    __shared__ float z3[16][64];
    __shared__ float h4[16][32];
    const int tid = threadIdx.x;
    const int b = blockIdx.y, n0 = blockIdx.x * 16;
    for (int idx = tid; idx < 4096; idx += 256){
        int nl = idx >> 8, i = idx & 255;
        int n = n0 + nl;
        float v = 0.f;
        if (n < NN){
            if      (i < 64)  v = HC[((size_t)b*NN + n)*64 + i];
            else if (i < 128) v = hlde[((size_t)b*NN + n)*64 + (i - 64)];
            else if (i < 192) v = x[((size_t)b*TT + 95)*NN + n] * xpw[i - 128] + xpb[0];
            else              v = gap[i - 192];
        }
        cat[nl][i] = v;
    }
    __syncthreads();
    {
        int j = tid & 127, half = tid >> 7;
        float acc[8];
        #pragma unroll
        for (int q = 0; q < 8; ++q) acc[q] = 0.f;
        for (int i = 0; i < 256; ++i){
            float w = g1w[j*256 + i];
            #pragma unroll
            for (int q = 0; q < 8; ++q) acc[q] += cat[half*8 + q][i] * w;
        }
        float bj = g1b[j];
        #pragma unroll
        for (int q = 0; q < 8; ++q) gl[half*8 + q][j] = gelu_f(acc[q] + bj);
    }
    __syncthreads();
    if (tid < 48){
        int nl = tid / 3, c = tid % 3;
        float s = g2b[c];
        for (int i = 0; i < 128; ++i) s += gl[nl][i] * g2w[c*128 + i];
        scl[nl][c] = s;
    }
    __syncthreads();
    if (tid < 16){
        float a = scl[tid][0], b2 = scl[tid][1], c2 = scl[tid][2];
        float mx = fmaxf(a, fmaxf(b2, c2));
        float e0 = expf(a - mx), e1 = expf(b2 - mx), e2 = expf(c2 - mx);
        float inv = 1.0f / (e0 + e1 + e2);
        gts[tid][0] = e0*inv; gts[tid][1] = e1*inv; gts[tid][2] = e2*inv;
    }
    __syncthreads();
    const int wg = tid >> 6, e = tid & 63;
    #pragma unroll
    for (int it = 0; it < 4; ++it){
        int nl = it*4 + wg;
        zl[nl][e] = gts[nl][0]*cat[nl][e] + gts[nl][1]*cat[nl][64 + e] + gts[nl][2]*cat[nl][128 + e];
    }
    __syncthreads();
    for (int it = 0; it < 4; ++it){
        int nl = it*4 + wg;
        float zp = opb[e];
        for (int d = 0; d < 64; ++d) zp += zl[nl][d] * opw[e*64 + d];
        float mu = zp;
        #pragma unroll
        for (int off = 1; off <= 32; off <<= 1) mu += __shfl_xor(mu, off);
        mu *= (1.0f/64.0f);
        float dv = zp - mu;
        float s2 = dv*dv;
        #pragma unroll
        for (int off = 1; off <= 32; off <<= 1) s2 += __shfl_xor(s2, off);
        float var = s2 * (1.0f/64.0f);
        float zn = dv / sqrtf(var + 1e-5f) * flg[e] + flb[e];
        z3[nl][e] = zn;
        float p = zn * dhw[e];
        #pragma unroll
        for (int off = 1; off <= 32; off <<= 1) p += __shfl_xor(p, off);
        if (e == 0){
            int n = n0 + nl;
            if (n < NN) DLT[b*NN + n] = p + dhb[0];
        }
    }
    __syncthreads();
    {
        int u = tid & 31, grp = tid >> 5;
        #pragma unroll
        for (int it = 0; it < 2; ++it){
            int nl = it*8 + grp;
            float s = u1b[u];
            for (int d = 0; d < 64; ++d) s += z3[nl][d] * u1w[u*64 + d];
            h4[nl][u] = gelu_f(s);
        }
    }
    __syncthreads();
    if (tid < 192){
        int o = tid % 12, nl = tid / 12;
        int n = n0 + nl;
        float s = u2b[o];
        for (int i = 0; i < 32; ++i) s += h4[nl][i] * u2w[o*32 + i];
        float sp = (s > 20.f) ? s : log1pf(expf(s));
        if (n < NN) sig[((size_t)b*NN + n)*12 + o] = sp + 1e-6f;
    }
}

// ---------------- 10. z_out = x + delta broadcast over t ----------------------
__global__ void k_zout(const float* __restrict__ x, const float* __restrict__ DLT,
                       float* __restrict__ out){
    int idx = blockIdx.x * 256 + threadIdx.x;
    if (idx >= BD*TT*NN) return;
    int b = idx / (TT*NN);
    int n = idx % NN;
    out[idx] = x[idx] + DLT[b*NN + n];
}

extern "C" void kernel_launch(void* const* d_in, const int* in_sizes, int n_in,
                              void* d_out, int out_size, void* d_ws, size_t ws_size,
                              hipStream_t stream){
    const float* x    = (const float*)d_in[0];
    const int*   sq   = (const int*)  d_in[1];
    const float* yq   = (const float*)d_in[2];
    const float* hlde = (const float*)d_in[3];
    const float* dww  = (const float*)d_in[4];
    const float* dwb  = (const float*)d_in[5];
    const float* pww  = (const float*)d_in[6];
    const float* pwb  = (const float*)d_in[7];
    const float* encg = (const float*)d_in[8];
    const float* encb = (const float*)d_in[9];
    const float* mb   = (const float*)d_in[10];
    const int*   ms   = (const int*)  d_in[11];
    const float* my   = (const float*)d_in[12];
    const float* ipw  = (const float*)d_in[13];
    const float* ipb  = (const float*)d_in[14];
    const float* aow  = (const float*)d_in[15];
    const float* aob  = (const float*)d_in[16];
    const float* pjw  = (const float*)d_in[17];
    const float* pjb  = (const float*)d_in[18];
    const float* gap  = (const float*)d_in[19];
    const float* xpw  = (const float*)d_in[20];
    const float* xpb  = (const float*)d_in[21];
    const float* g1w  = (const float*)d_in[22];
    const float* g1b  = (const float*)d_in[23];
    const float* g2w  = (const float*)d_in[24];
    const float* g2b  = (const float*)d_in[25];
    const float* opw  = (const float*)d_in[26];
    const float* opb  = (const float*)d_in[27];
    const float* dhw  = (const float*)d_in[28];
    const float* dhb  = (const float*)d_in[29];
    const float* flg  = (const float*)d_in[30];
    const float* flb  = (const float*)d_in[31];
    const float* u1w  = (const float*)d_in[32];
    const float* u1b  = (const float*)d_in[33];
    const float* u2w  = (const float*)d_in[34];
    const float* u2b  = (const float*)d_in[35];

    // ws layout (overlaps exploit lifetimes):
    //  [0 .. 3,014,656)       HT (k_conv -> k_gemm) / P (k_sim -> k_topk, after gemm)
    //  [3,014,656 ..)         QB
    //  [5,947,392 ..)         QI
    //  [5,947,648 ..)         TK
    //  [5,948,160 ..)         DLT
    //  [5,993,984 ..)         PSS
    //  [6,070,528 ..)         Abf (k_cast -> k_gemm; 67,452,928 B)
    //                         OWB/HCB overlap Abf (used only after gemm)
    char* ws = (char*)d_ws;
    unsigned short* HT = (unsigned short*)(ws + 0);
    float* P    = (float*)(ws + 0);
    float* QB   = (float*)(ws + 3014656);
    float* QI   = (float*)(ws + 5947392);
    int*   TK   = (int*)  (ws + 5947648);
    float* DLT  = (float*)(ws + 5948160);
    float* PSS  = (float*)(ws + 5993984);
    unsigned short* Abf = (unsigned short*)(ws + 6070528);
    float* OWB  = (float*)(ws + 6070528);
    float* HCB  = (float*)(ws + 6070528 + 2932736);

    float* out = (float*)d_out;
    float* sig = out + 1099776;

    k_cast <<<dim3(16468),  dim3(256), 0, stream>>>(pww, Abf);
    k_conv <<<dim3(5888),   dim3(256), 0, stream>>>(x, dww, dwb, HT);
    k_gemm <<<dim3(8, 358), dim3(256), 0, stream>>>(Abf, pwb, HT, QB);
    k_ln   <<<dim3(2864),   dim3(256), 0, stream>>>(QB, encg, encb);
    k_qnorm<<<dim3(16),     dim3(256), 0, stream>>>(QB, QI);
    k_sim  <<<dim3(75, 16), dim3(256), 0, stream>>>(mb, QB, P, PSS);
    k_topk <<<dim3(16),     dim3(256), 0, stream>>>(P, PSS, QI, sq, yq, ms, my, TK);
    k_attn <<<dim3(45, 16), dim3(256), 0, stream>>>(QB, mb, TK, ipw, ipb, OWB);
    k_hcem <<<dim3(2864),   dim3(256), 0, stream>>>(OWB, aow, aob, pjw, pjb, HCB);
    k_final<<<dim3(45, 16), dim3(256), 0, stream>>>(HCB, hlde, x, gap, xpw, xpb,
            g1w, g1b, g2w, g2b, opw, opb, flg, flb, u1w, u1b, u2w, u2b, dhw, dhb,
            sig, DLT);
    k_zout <<<dim3(4296),   dim3(256), 0, stream>>>(x, DLT, out);
}